// Round 1
// baseline (1074.483 us; speedup 1.0000x reference)
//
#include <hip/hip_runtime.h>

// GNN layer: out = segment_sum(feat[src], dst) @ W^T + b
// Inputs: feat [N,64] f32, src [E] i32, dst [E] i32, W [64,64] f32, b [64] f32
// Output: [N,64] f32.  Aggregation done in-place in d_out (zeroed first),
// then a per-node in-place linear transform.

#define DIM 64

__global__ void zero_kernel(float4* __restrict__ p, long n4) {
    long i = (long)blockIdx.x * blockDim.x + threadIdx.x;
    long stride = (long)gridDim.x * blockDim.x;
    for (; i < n4; i += stride) p[i] = make_float4(0.f, 0.f, 0.f, 0.f);
}

// 16 threads per edge; each thread handles one float4 (4 columns) of the row.
__global__ void scatter_kernel(const float* __restrict__ feat,
                               const int* __restrict__ src,
                               const int* __restrict__ dst,
                               float* __restrict__ agg,
                               int n_edges) {
    long tid = (long)blockIdx.x * blockDim.x + threadIdx.x;
    long total = (long)n_edges * 16;
    if (tid >= total) return;
    int e    = (int)(tid >> 4);
    int part = (int)(tid & 15);
    int s = src[e];
    int d = dst[e];
    const float4* fr = (const float4*)(feat + (long)s * DIM);
    float4 v = fr[part];
    float* dp = agg + (long)d * DIM + part * 4;
    atomicAdd(dp + 0, v.x);
    atomicAdd(dp + 1, v.y);
    atomicAdd(dp + 2, v.z);
    atomicAdd(dp + 3, v.w);
}

// One wave per node: lane o computes out[n][o] = b[o] + sum_d agg[n][d]*W[o][d].
// W staged transposed in LDS (lane-stride-1 reads, conflict-free); agg row
// staged in LDS (broadcast reads are free). In-place on d_out.
__global__ void linear_kernel(float* __restrict__ io,
                              const float* __restrict__ W,
                              const float* __restrict__ b,
                              int n_nodes) {
    __shared__ float Wt[DIM * DIM];     // Wt[d][o] = W[o][d]
    __shared__ float arow[4][DIM];
    int t = threadIdx.x;
    for (int i = t; i < DIM * DIM; i += 256) {
        int o = i >> 6, d = i & 63;
        Wt[d * DIM + o] = W[i];
    }
    int wave = t >> 6;
    int lane = t & 63;
    int node = blockIdx.x * 4 + wave;
    float a = 0.f;
    if (node < n_nodes) a = io[(long)node * DIM + lane];
    arow[wave][lane] = a;
    __syncthreads();
    if (node >= n_nodes) return;
    float acc = b[lane];
#pragma unroll
    for (int d = 0; d < DIM; ++d)
        acc += arow[wave][d] * Wt[d * DIM + lane];
    io[(long)node * DIM + lane] = acc;
}

extern "C" void kernel_launch(void* const* d_in, const int* in_sizes, int n_in,
                              void* d_out, int out_size, void* d_ws, size_t ws_size,
                              hipStream_t stream) {
    const float* feat = (const float*)d_in[0];
    const int*   src  = (const int*)d_in[1];
    const int*   dst  = (const int*)d_in[2];
    const float* W    = (const float*)d_in[3];
    const float* b    = (const float*)d_in[4];
    float* out = (float*)d_out;

    int n_nodes = in_sizes[0] / DIM;
    int n_edges = in_sizes[1];

    // A: zero the aggregation buffer (d_out)
    long n4 = (long)n_nodes * DIM / 4;
    zero_kernel<<<2048, 256, 0, stream>>>((float4*)out, n4);

    // B: scatter-add feat[src] into out[dst]
    long total_threads = (long)n_edges * 16;
    int grid_b = (int)((total_threads + 255) / 256);
    scatter_kernel<<<grid_b, 256, 0, stream>>>(feat, src, dst, out, n_edges);

    // C: in-place linear, one wave per node
    int grid_c = (n_nodes + 3) / 4;
    linear_kernel<<<grid_c, 256, 0, stream>>>(out, W, b, n_nodes);
}

// Round 2
// 337.903 us; speedup vs baseline: 3.1799x; 3.1799x over previous
//
#include <hip/hip_runtime.h>

// GNN layer: out = segment_sum(feat[src], dst) @ W^T + b
// Strategy: counting-sort edges by dst, then gather-side reduction (no float
// atomics), fused with the 64x64 linear.
//
// Workspace layout (ints): starts[N+1] (also used as counts), cursors[N],
// blocksums[64], sorted_src[E].  ~4.8 MB total.

#define DIM 64
#define CHUNK 2048   // counts per scan block (256 threads x 8)

__global__ void zero_ints(int* __restrict__ p, int n) {
    int i = blockIdx.x * blockDim.x + threadIdx.x;
    int stride = gridDim.x * blockDim.x;
    for (; i < n; i += stride) p[i] = 0;
}

__global__ void hist_kernel(const int* __restrict__ dst, int* __restrict__ counts,
                            int n_edges) {
    int i = blockIdx.x * blockDim.x + threadIdx.x;
    int stride = gridDim.x * blockDim.x;
    for (; i < n_edges; i += stride) atomicAdd(&counts[dst[i]], 1);
}

// Per-chunk totals (for the two-level exclusive scan).
__global__ void chunk_sums(const int* __restrict__ counts, int* __restrict__ blocksums,
                           int n) {
    __shared__ int red[256];
    int base = blockIdx.x * CHUNK + threadIdx.x * 8;
    int s = 0;
#pragma unroll
    for (int j = 0; j < 8; ++j) { int i = base + j; if (i < n) s += counts[i]; }
    red[threadIdx.x] = s;
    __syncthreads();
    for (int off = 128; off > 0; off >>= 1) {
        if (threadIdx.x < off) red[threadIdx.x] += red[threadIdx.x + off];
        __syncthreads();
    }
    if (threadIdx.x == 0) blocksums[blockIdx.x] = red[0];
}

// Exclusive scan of <=256 elements, single block.
__global__ void scan_small(int* __restrict__ data, int n) {
    __shared__ int tmp[256];
    int t = threadIdx.x;
    int v = (t < n) ? data[t] : 0;
    tmp[t] = v;
    __syncthreads();
    for (int off = 1; off < 256; off <<= 1) {
        int x = (t >= off) ? tmp[t - off] : 0;
        __syncthreads();
        tmp[t] += x;
        __syncthreads();
    }
    if (t < n) data[t] = tmp[t] - v;   // exclusive
}

// Per-chunk exclusive scan + chunk offset -> starts & cursors.
// counts and starts may alias: each block reads only its own chunk's counts
// before overwriting them.
__global__ void scan_write(const int* __restrict__ counts,
                           const int* __restrict__ blocksums,
                           int* __restrict__ starts, int* __restrict__ cursors,
                           int n, int n_edges) {
    __shared__ int tsum[256];
    int t = threadIdx.x;
    int base = blockIdx.x * CHUNK + t * 8;
    int c[8];
    int s = 0;
#pragma unroll
    for (int j = 0; j < 8; ++j) { int i = base + j; c[j] = (i < n) ? counts[i] : 0; s += c[j]; }
    tsum[t] = s;
    __syncthreads();
    for (int off = 1; off < 256; off <<= 1) {
        int x = (t >= off) ? tsum[t - off] : 0;
        __syncthreads();
        tsum[t] += x;
        __syncthreads();
    }
    int run = blocksums[blockIdx.x] + (tsum[t] - s);   // exclusive thread offset
#pragma unroll
    for (int j = 0; j < 8; ++j) {
        int i = base + j;
        if (i < n) { starts[i] = run; cursors[i] = run; run += c[j]; }
    }
    if (blockIdx.x == 0 && t == 0) starts[n] = n_edges;
}

__global__ void bucket_scatter(const int* __restrict__ src, const int* __restrict__ dst,
                               int* __restrict__ cursors, int* __restrict__ sorted_src,
                               int n_edges) {
    int i = blockIdx.x * blockDim.x + threadIdx.x;
    int stride = gridDim.x * blockDim.x;
    for (; i < n_edges; i += stride) {
        int d = dst[i];
        int pos = atomicAdd(&cursors[d], 1);
        sorted_src[pos] = src[i];
    }
}

// One wave per node: sum feat rows of the node's bucket, then apply linear.
__global__ void gather_linear(const float* __restrict__ feat,
                              const int* __restrict__ starts,
                              const int* __restrict__ sorted_src,
                              const float* __restrict__ W,
                              const float* __restrict__ b,
                              float* __restrict__ out, int n_nodes) {
    __shared__ float Wt[DIM * DIM];     // Wt[d][o] = W[o][d]
    __shared__ float arow[4][DIM];
    int t = threadIdx.x;
    for (int i = t; i < DIM * DIM; i += 256) {
        int o = i >> 6, d = i & 63;
        Wt[d * DIM + o] = W[i];
    }
    int wave = t >> 6, lane = t & 63;
    int node = blockIdx.x * 4 + wave;
    float acc = 0.f;
    if (node < n_nodes) {
        int e0 = starts[node], e1 = starts[node + 1];
        for (int e = e0; e < e1; ++e) {
            int s = sorted_src[e];
            acc += feat[(long)s * DIM + lane];
        }
    }
    arow[wave][lane] = acc;
    __syncthreads();
    if (node >= n_nodes) return;
    float r = b[lane];
#pragma unroll
    for (int d = 0; d < DIM; ++d) r += arow[wave][d] * Wt[d * DIM + lane];
    out[(long)node * DIM + lane] = r;
}

extern "C" void kernel_launch(void* const* d_in, const int* in_sizes, int n_in,
                              void* d_out, int out_size, void* d_ws, size_t ws_size,
                              hipStream_t stream) {
    const float* feat = (const float*)d_in[0];
    const int*   src  = (const int*)d_in[1];
    const int*   dst  = (const int*)d_in[2];
    const float* W    = (const float*)d_in[3];
    const float* b    = (const float*)d_in[4];
    float* out = (float*)d_out;

    int n_nodes = in_sizes[0] / DIM;
    int n_edges = in_sizes[1];

    // workspace layout
    char* ws = (char*)d_ws;
    size_t off = 0;
    int* starts = (int*)(ws + off);             // N+1 ints (also counts)
    off += ((size_t)(n_nodes + 1) * 4 + 255) & ~(size_t)255;
    int* cursors = (int*)(ws + off);            // N ints
    off += ((size_t)n_nodes * 4 + 255) & ~(size_t)255;
    int* blocksums = (int*)(ws + off);          // <=256 ints
    off += 1024;
    int* sorted_src = (int*)(ws + off);         // E ints

    int nchunks = (n_nodes + CHUNK - 1) / CHUNK;

    zero_ints<<<(n_nodes + 256) / 256, 256, 0, stream>>>(starts, n_nodes + 1);
    hist_kernel<<<2048, 256, 0, stream>>>(dst, starts, n_edges);
    chunk_sums<<<nchunks, 256, 0, stream>>>(starts, blocksums, n_nodes);
    scan_small<<<1, 256, 0, stream>>>(blocksums, nchunks);
    scan_write<<<nchunks, 256, 0, stream>>>(starts, blocksums, starts, cursors,
                                            n_nodes, n_edges);
    bucket_scatter<<<2048, 256, 0, stream>>>(src, dst, cursors, sorted_src, n_edges);
    gather_linear<<<(n_nodes + 3) / 4, 256, 0, stream>>>(feat, starts, sorted_src,
                                                         W, b, out, n_nodes);
}

// Round 3
// 332.110 us; speedup vs baseline: 3.2353x; 1.0174x over previous
//
#include <hip/hip_runtime.h>

// GNN layer: out = segment_sum(feat[src], dst) @ W^T + b
// Counting-sort edges by dst, then gather-side reduction fused with the
// 64x64 linear.  Gather uses 4 edge-groups x 16 lanes x float4 per wave for
// 4-8 cache-line streams in flight (latency hiding), then shfl_xor reduce.

#define DIM 64
#define CHUNK 2048   // counts per scan block (256 threads x 8)

__global__ void zero_ints(int* __restrict__ p, int n) {
    int i = blockIdx.x * blockDim.x + threadIdx.x;
    int stride = gridDim.x * blockDim.x;
    for (; i < n; i += stride) p[i] = 0;
}

__global__ void hist_kernel(const int* __restrict__ dst, int* __restrict__ counts,
                            int n_edges) {
    int n4 = n_edges >> 2;
    int i = blockIdx.x * blockDim.x + threadIdx.x;
    int stride = gridDim.x * blockDim.x;
    const int4* d4p = (const int4*)dst;
    for (; i < n4; i += stride) {
        int4 d = d4p[i];
        atomicAdd(&counts[d.x], 1);
        atomicAdd(&counts[d.y], 1);
        atomicAdd(&counts[d.z], 1);
        atomicAdd(&counts[d.w], 1);
    }
    // tail
    int base = n4 << 2;
    int t = base + (blockIdx.x * blockDim.x + threadIdx.x);
    if (t < n_edges && blockIdx.x * blockDim.x + threadIdx.x < (n_edges - base))
        atomicAdd(&counts[dst[t]], 1);
}

// Per-chunk totals (for the two-level exclusive scan).
__global__ void chunk_sums(const int* __restrict__ counts, int* __restrict__ blocksums,
                           int n) {
    __shared__ int red[256];
    int base = blockIdx.x * CHUNK + threadIdx.x * 8;
    int s = 0;
#pragma unroll
    for (int j = 0; j < 8; ++j) { int i = base + j; if (i < n) s += counts[i]; }
    red[threadIdx.x] = s;
    __syncthreads();
    for (int off = 128; off > 0; off >>= 1) {
        if (threadIdx.x < off) red[threadIdx.x] += red[threadIdx.x + off];
        __syncthreads();
    }
    if (threadIdx.x == 0) blocksums[blockIdx.x] = red[0];
}

// Exclusive scan of <=256 elements, single block.
__global__ void scan_small(int* __restrict__ data, int n) {
    __shared__ int tmp[256];
    int t = threadIdx.x;
    int v = (t < n) ? data[t] : 0;
    tmp[t] = v;
    __syncthreads();
    for (int off = 1; off < 256; off <<= 1) {
        int x = (t >= off) ? tmp[t - off] : 0;
        __syncthreads();
        tmp[t] += x;
        __syncthreads();
    }
    if (t < n) data[t] = tmp[t] - v;   // exclusive
}

// Per-chunk exclusive scan + chunk offset -> starts & cursors.
__global__ void scan_write(const int* __restrict__ counts,
                           const int* __restrict__ blocksums,
                           int* __restrict__ starts, int* __restrict__ cursors,
                           int n, int n_edges) {
    __shared__ int tsum[256];
    int t = threadIdx.x;
    int base = blockIdx.x * CHUNK + t * 8;
    int c[8];
    int s = 0;
#pragma unroll
    for (int j = 0; j < 8; ++j) { int i = base + j; c[j] = (i < n) ? counts[i] : 0; s += c[j]; }
    tsum[t] = s;
    __syncthreads();
    for (int off = 1; off < 256; off <<= 1) {
        int x = (t >= off) ? tsum[t - off] : 0;
        __syncthreads();
        tsum[t] += x;
        __syncthreads();
    }
    int run = blocksums[blockIdx.x] + (tsum[t] - s);   // exclusive thread offset
#pragma unroll
    for (int j = 0; j < 8; ++j) {
        int i = base + j;
        if (i < n) { starts[i] = run; cursors[i] = run; run += c[j]; }
    }
    if (blockIdx.x == 0 && t == 0) starts[n] = n_edges;
}

__global__ void bucket_scatter(const int* __restrict__ src, const int* __restrict__ dst,
                               int* __restrict__ cursors, int* __restrict__ sorted_src,
                               int n_edges) {
    int n4 = n_edges >> 2;
    int i = blockIdx.x * blockDim.x + threadIdx.x;
    int stride = gridDim.x * blockDim.x;
    const int4* s4p = (const int4*)src;
    const int4* d4p = (const int4*)dst;
    for (; i < n4; i += stride) {
        int4 s = s4p[i];
        int4 d = d4p[i];
        sorted_src[atomicAdd(&cursors[d.x], 1)] = s.x;
        sorted_src[atomicAdd(&cursors[d.y], 1)] = s.y;
        sorted_src[atomicAdd(&cursors[d.z], 1)] = s.z;
        sorted_src[atomicAdd(&cursors[d.w], 1)] = s.w;
    }
    int base = n4 << 2;
    int r = blockIdx.x * blockDim.x + threadIdx.x;
    int t = base + r;
    if (t < n_edges && r < (n_edges - base))
        sorted_src[atomicAdd(&cursors[dst[t]], 1)] = src[t];
}

// One wave per node.  Lane layout: sub = lane>>4 (edge group), part = lane&15
// (float4 column chunk).  4 rows in flight, unroll 2 -> up to 8 streams.
__global__ void gather_linear(const float* __restrict__ feat,
                              const int* __restrict__ starts,
                              const int* __restrict__ sorted_src,
                              const float* __restrict__ W,
                              const float* __restrict__ b,
                              float* __restrict__ out, int n_nodes) {
    __shared__ float Wt[DIM * DIM];     // Wt[d][o] = W[o][d]
    __shared__ float arow[4][DIM];
    int t = threadIdx.x;
    for (int i = t; i < DIM * DIM; i += 256) {
        int o = i >> 6, d = i & 63;
        Wt[d * DIM + o] = W[i];
    }
    __syncthreads();
    int wave = t >> 6, lane = t & 63;
    int node = blockIdx.x * 4 + wave;
    if (node >= n_nodes) return;

    int sub = lane >> 4;       // 0..3
    int part = lane & 15;      // 0..15 -> float4 chunk

    float4 acc = make_float4(0.f, 0.f, 0.f, 0.f);
    float4 acc2 = make_float4(0.f, 0.f, 0.f, 0.f);
    int e0 = starts[node], e1 = starts[node + 1];
    int e = e0 + sub;
    for (; e + 4 < e1; e += 8) {
        int s0 = sorted_src[e];
        int s1 = sorted_src[e + 4];
        float4 v0 = *(const float4*)(feat + (long)s0 * DIM + part * 4);
        float4 v1 = *(const float4*)(feat + (long)s1 * DIM + part * 4);
        acc.x += v0.x; acc.y += v0.y; acc.z += v0.z; acc.w += v0.w;
        acc2.x += v1.x; acc2.y += v1.y; acc2.z += v1.z; acc2.w += v1.w;
    }
    if (e < e1) {
        int s0 = sorted_src[e];
        float4 v0 = *(const float4*)(feat + (long)s0 * DIM + part * 4);
        acc.x += v0.x; acc.y += v0.y; acc.z += v0.z; acc.w += v0.w;
    }
    acc.x += acc2.x; acc.y += acc2.y; acc.z += acc2.z; acc.w += acc2.w;

    // reduce across the 4 edge-groups (lanes with same part)
#pragma unroll
    for (int m = 16; m <= 32; m <<= 1) {
        acc.x += __shfl_xor(acc.x, m);
        acc.y += __shfl_xor(acc.y, m);
        acc.z += __shfl_xor(acc.z, m);
        acc.w += __shfl_xor(acc.w, m);
    }
    if (sub == 0) *(float4*)(&arow[wave][part * 4]) = acc;
    // intra-wave LDS dependency: compiler inserts lgkmcnt wait; no barrier
    // needed (arow[wave] is written and read by the same wave only).

    float r = b[lane];
#pragma unroll
    for (int d = 0; d < DIM; ++d) r += arow[wave][d] * Wt[d * DIM + lane];
    out[(long)node * DIM + lane] = r;
}

extern "C" void kernel_launch(void* const* d_in, const int* in_sizes, int n_in,
                              void* d_out, int out_size, void* d_ws, size_t ws_size,
                              hipStream_t stream) {
    const float* feat = (const float*)d_in[0];
    const int*   src  = (const int*)d_in[1];
    const int*   dst  = (const int*)d_in[2];
    const float* W    = (const float*)d_in[3];
    const float* b    = (const float*)d_in[4];
    float* out = (float*)d_out;

    int n_nodes = in_sizes[0] / DIM;
    int n_edges = in_sizes[1];

    // workspace layout
    char* ws = (char*)d_ws;
    size_t off = 0;
    int* starts = (int*)(ws + off);             // N+1 ints (also counts)
    off += ((size_t)(n_nodes + 1) * 4 + 255) & ~(size_t)255;
    int* cursors = (int*)(ws + off);            // N ints
    off += ((size_t)n_nodes * 4 + 255) & ~(size_t)255;
    int* blocksums = (int*)(ws + off);          // <=256 ints
    off += 1024;
    int* sorted_src = (int*)(ws + off);         // E ints

    int nchunks = (n_nodes + CHUNK - 1) / CHUNK;

    zero_ints<<<(n_nodes + 256) / 256, 256, 0, stream>>>(starts, n_nodes + 1);
    hist_kernel<<<1024, 256, 0, stream>>>(dst, starts, n_edges);
    chunk_sums<<<nchunks, 256, 0, stream>>>(starts, blocksums, n_nodes);
    scan_small<<<1, 256, 0, stream>>>(blocksums, nchunks);
    scan_write<<<nchunks, 256, 0, stream>>>(starts, blocksums, starts, cursors,
                                            n_nodes, n_edges);
    bucket_scatter<<<1024, 256, 0, stream>>>(src, dst, cursors, sorted_src, n_edges);
    gather_linear<<<(n_nodes + 3) / 4, 256, 0, stream>>>(feat, starts, sorted_src,
                                                         W, b, out, n_nodes);
}

// Round 4
// 182.131 us; speedup vs baseline: 5.8995x; 1.8235x over previous
//
#include <hip/hip_runtime.h>

// GNN layer: out = segment_sum(feat[src], dst) @ W^T + b
// Counting-sort edges by dst, then gather-side reduction fused with the
// 64x64 linear.  Round 4: fix the 64-way LDS bank conflict in the Wt
// transpose staging (pad stride to 65), float4 arow broadcasts, persistent
// gather_linear blocks (stage W once per block, grid-stride nodes).

#define DIM 64
#define WT_LD 65     // padded leading dim: 65 % 32 == 1 -> conflict-free
#define CHUNK 2048   // counts per scan block (256 threads x 8)

__global__ void zero_ints(int* __restrict__ p, int n) {
    int i = blockIdx.x * blockDim.x + threadIdx.x;
    int stride = gridDim.x * blockDim.x;
    for (; i < n; i += stride) p[i] = 0;
}

__global__ void hist_kernel(const int* __restrict__ dst, int* __restrict__ counts,
                            int n_edges) {
    int n4 = n_edges >> 2;
    int i = blockIdx.x * blockDim.x + threadIdx.x;
    int stride = gridDim.x * blockDim.x;
    const int4* d4p = (const int4*)dst;
    for (; i < n4; i += stride) {
        int4 d = d4p[i];
        atomicAdd(&counts[d.x], 1);
        atomicAdd(&counts[d.y], 1);
        atomicAdd(&counts[d.z], 1);
        atomicAdd(&counts[d.w], 1);
    }
    int base = n4 << 2;
    int r = blockIdx.x * blockDim.x + threadIdx.x;
    int t = base + r;
    if (t < n_edges && r < (n_edges - base)) atomicAdd(&counts[dst[t]], 1);
}

// Per-chunk totals (for the two-level exclusive scan).
__global__ void chunk_sums(const int* __restrict__ counts, int* __restrict__ blocksums,
                           int n) {
    __shared__ int red[256];
    int base = blockIdx.x * CHUNK + threadIdx.x * 8;
    int s = 0;
#pragma unroll
    for (int j = 0; j < 8; ++j) { int i = base + j; if (i < n) s += counts[i]; }
    red[threadIdx.x] = s;
    __syncthreads();
    for (int off = 128; off > 0; off >>= 1) {
        if (threadIdx.x < off) red[threadIdx.x] += red[threadIdx.x + off];
        __syncthreads();
    }
    if (threadIdx.x == 0) blocksums[blockIdx.x] = red[0];
}

// Exclusive scan of <=256 elements, single block.
__global__ void scan_small(int* __restrict__ data, int n) {
    __shared__ int tmp[256];
    int t = threadIdx.x;
    int v = (t < n) ? data[t] : 0;
    tmp[t] = v;
    __syncthreads();
    for (int off = 1; off < 256; off <<= 1) {
        int x = (t >= off) ? tmp[t - off] : 0;
        __syncthreads();
        tmp[t] += x;
        __syncthreads();
    }
    if (t < n) data[t] = tmp[t] - v;   // exclusive
}

// Per-chunk exclusive scan + chunk offset -> starts & cursors.
__global__ void scan_write(const int* __restrict__ counts,
                           const int* __restrict__ blocksums,
                           int* __restrict__ starts, int* __restrict__ cursors,
                           int n, int n_edges) {
    __shared__ int tsum[256];
    int t = threadIdx.x;
    int base = blockIdx.x * CHUNK + t * 8;
    int c[8];
    int s = 0;
#pragma unroll
    for (int j = 0; j < 8; ++j) { int i = base + j; c[j] = (i < n) ? counts[i] : 0; s += c[j]; }
    tsum[t] = s;
    __syncthreads();
    for (int off = 1; off < 256; off <<= 1) {
        int x = (t >= off) ? tsum[t - off] : 0;
        __syncthreads();
        tsum[t] += x;
        __syncthreads();
    }
    int run = blocksums[blockIdx.x] + (tsum[t] - s);   // exclusive thread offset
#pragma unroll
    for (int j = 0; j < 8; ++j) {
        int i = base + j;
        if (i < n) { starts[i] = run; cursors[i] = run; run += c[j]; }
    }
    if (blockIdx.x == 0 && t == 0) starts[n] = n_edges;
}

__global__ void bucket_scatter(const int* __restrict__ src, const int* __restrict__ dst,
                               int* __restrict__ cursors, int* __restrict__ sorted_src,
                               int n_edges) {
    int n4 = n_edges >> 2;
    int i = blockIdx.x * blockDim.x + threadIdx.x;
    int stride = gridDim.x * blockDim.x;
    const int4* s4p = (const int4*)src;
    const int4* d4p = (const int4*)dst;
    for (; i < n4; i += stride) {
        int4 s = s4p[i];
        int4 d = d4p[i];
        sorted_src[atomicAdd(&cursors[d.x], 1)] = s.x;
        sorted_src[atomicAdd(&cursors[d.y], 1)] = s.y;
        sorted_src[atomicAdd(&cursors[d.z], 1)] = s.z;
        sorted_src[atomicAdd(&cursors[d.w], 1)] = s.w;
    }
    int base = n4 << 2;
    int r = blockIdx.x * blockDim.x + threadIdx.x;
    int t = base + r;
    if (t < n_edges && r < (n_edges - base))
        sorted_src[atomicAdd(&cursors[dst[t]], 1)] = src[t];
}

// Persistent blocks: stage W^T in LDS once (padded stride -> no bank
// conflicts), then grid-stride over nodes, 1 wave per node.
// Lane layout in gather: sub = lane>>4 (edge group), part = lane&15 (float4).
__global__ void __launch_bounds__(256, 4)
gather_linear(const float* __restrict__ feat,
              const int* __restrict__ starts,
              const int* __restrict__ sorted_src,
              const float* __restrict__ W,
              const float* __restrict__ b,
              float* __restrict__ out, int n_nodes) {
    __shared__ float Wt[DIM * WT_LD];   // Wt[d][o] = W[o][d], stride 65
    __shared__ float arow[4][DIM];
    int t = threadIdx.x;
    for (int i = t; i < DIM * DIM; i += 256) {
        int o = i >> 6, d = i & 63;
        Wt[d * WT_LD + o] = W[i];       // addr = lane*65 + o: all banks, 2-way
    }
    __syncthreads();
    int wave = t >> 6, lane = t & 63;
    int sub = lane >> 4;       // 0..3
    int part = lane & 15;      // 0..15 -> float4 chunk
    float bl = b[lane];

    for (int node = blockIdx.x * 4 + wave; node < n_nodes; node += gridDim.x * 4) {
        float4 acc = make_float4(0.f, 0.f, 0.f, 0.f);
        float4 acc2 = make_float4(0.f, 0.f, 0.f, 0.f);
        int e0 = starts[node], e1 = starts[node + 1];
        int e = e0 + sub;
        for (; e + 4 < e1; e += 8) {
            int s0 = sorted_src[e];
            int s1 = sorted_src[e + 4];
            float4 v0 = *(const float4*)(feat + (long)s0 * DIM + part * 4);
            float4 v1 = *(const float4*)(feat + (long)s1 * DIM + part * 4);
            acc.x += v0.x; acc.y += v0.y; acc.z += v0.z; acc.w += v0.w;
            acc2.x += v1.x; acc2.y += v1.y; acc2.z += v1.z; acc2.w += v1.w;
        }
        if (e < e1) {
            int s0 = sorted_src[e];
            float4 v0 = *(const float4*)(feat + (long)s0 * DIM + part * 4);
            acc.x += v0.x; acc.y += v0.y; acc.z += v0.z; acc.w += v0.w;
        }
        acc.x += acc2.x; acc.y += acc2.y; acc.z += acc2.z; acc.w += acc2.w;

        // reduce across the 4 edge-groups (lanes with same part)
#pragma unroll
        for (int m = 16; m <= 32; m <<= 1) {
            acc.x += __shfl_xor(acc.x, m);
            acc.y += __shfl_xor(acc.y, m);
            acc.z += __shfl_xor(acc.z, m);
            acc.w += __shfl_xor(acc.w, m);
        }
        if (sub == 0) *(float4*)(&arow[wave][part * 4]) = acc;
        // same-wave LDS write->read: compiler inserts lgkmcnt wait, no barrier.

        float r = bl;
#pragma unroll
        for (int dd = 0; dd < 16; ++dd) {
            float4 a4 = *(const float4*)(&arow[wave][dd * 4]);   // broadcast
            r += a4.x * Wt[(dd * 4 + 0) * WT_LD + lane];
            r += a4.y * Wt[(dd * 4 + 1) * WT_LD + lane];
            r += a4.z * Wt[(dd * 4 + 2) * WT_LD + lane];
            r += a4.w * Wt[(dd * 4 + 3) * WT_LD + lane];
        }
        out[(long)node * DIM + lane] = r;
    }
}

extern "C" void kernel_launch(void* const* d_in, const int* in_sizes, int n_in,
                              void* d_out, int out_size, void* d_ws, size_t ws_size,
                              hipStream_t stream) {
    const float* feat = (const float*)d_in[0];
    const int*   src  = (const int*)d_in[1];
    const int*   dst  = (const int*)d_in[2];
    const float* W    = (const float*)d_in[3];
    const float* b    = (const float*)d_in[4];
    float* out = (float*)d_out;

    int n_nodes = in_sizes[0] / DIM;
    int n_edges = in_sizes[1];

    // workspace layout
    char* ws = (char*)d_ws;
    size_t off = 0;
    int* starts = (int*)(ws + off);             // N+1 ints (also counts)
    off += ((size_t)(n_nodes + 1) * 4 + 255) & ~(size_t)255;
    int* cursors = (int*)(ws + off);            // N ints
    off += ((size_t)n_nodes * 4 + 255) & ~(size_t)255;
    int* blocksums = (int*)(ws + off);          // <=256 ints
    off += 1024;
    int* sorted_src = (int*)(ws + off);         // E ints

    int nchunks = (n_nodes + CHUNK - 1) / CHUNK;

    zero_ints<<<(n_nodes + 256) / 256, 256, 0, stream>>>(starts, n_nodes + 1);
    hist_kernel<<<1024, 256, 0, stream>>>(dst, starts, n_edges);
    chunk_sums<<<nchunks, 256, 0, stream>>>(starts, blocksums, n_nodes);
    scan_small<<<1, 256, 0, stream>>>(blocksums, nchunks);
    scan_write<<<nchunks, 256, 0, stream>>>(starts, blocksums, starts, cursors,
                                            n_nodes, n_edges);
    bucket_scatter<<<1024, 256, 0, stream>>>(src, dst, cursors, sorted_src, n_edges);
    gather_linear<<<2048, 256, 0, stream>>>(feat, starts, sorted_src,
                                            W, b, out, n_nodes);
}

// Round 5
// 131.190 us; speedup vs baseline: 8.1903x; 1.3883x over previous
//
#include <hip/hip_runtime.h>

// GNN layer: out = segment_sum(feat[src], dst) @ W^T + b
// Round 5: slab-based design.  Edges are partitioned into 128-node slabs by
// dst (coarse counting sort with tile-local LDS grouping -> short contiguous
// write runs, no 64B-line write amplification).  Each slab's consumer block
// then counting-sorts its ~1280 edges by exact dst entirely in LDS and runs
// the fused gather + 64x64 linear.  One packed u32 per edge:
// (dst&127)<<25 | src  (src < 2^17).

#define DIM 64
#define WT_LD 65          // padded: 65 % 32 == 1 -> conflict-free transpose
#define SLAB_SHIFT 7
#define SLAB_NODES 128
#define MAX_SLABS 800     // >= ceil(100000/128) = 782
#define SLAB_CAP 2048     // LDS capacity of edges per slab (avg 1280, +20 sigma)
#define PART_T 16384      // edges per partition tile

__global__ void zero_counts(int* __restrict__ counts) {
    int t = threadIdx.x;
    if (t < MAX_SLABS) counts[t] = 0;
}

__global__ void slab_hist(const int* __restrict__ dst, int* __restrict__ counts,
                          int n_edges, int nslab) {
    __shared__ int c[MAX_SLABS];
    for (int i = threadIdx.x; i < nslab; i += blockDim.x) c[i] = 0;
    __syncthreads();
    int n4 = n_edges >> 2;
    const int4* d4 = (const int4*)dst;
    for (int i = blockIdx.x * blockDim.x + threadIdx.x; i < n4;
         i += gridDim.x * blockDim.x) {
        int4 d = d4[i];
        atomicAdd(&c[d.x >> SLAB_SHIFT], 1);
        atomicAdd(&c[d.y >> SLAB_SHIFT], 1);
        atomicAdd(&c[d.z >> SLAB_SHIFT], 1);
        atomicAdd(&c[d.w >> SLAB_SHIFT], 1);
    }
    int base = n4 << 2;
    int r = base + blockIdx.x * blockDim.x + threadIdx.x;
    if (r < n_edges) atomicAdd(&c[dst[r] >> SLAB_SHIFT], 1);
    __syncthreads();
    for (int i = threadIdx.x; i < nslab; i += blockDim.x)
        if (c[i]) atomicAdd(&counts[i], c[i]);
}

// Single-block exclusive scan of nslab (<=1024) counts -> starts & cursors.
__global__ void scan_slabs(const int* __restrict__ counts, int* __restrict__ starts,
                           int* __restrict__ cursors, int nslab) {
    __shared__ int tmp[1024];
    int t = threadIdx.x;
    int v = (t < nslab) ? counts[t] : 0;
    tmp[t] = v;
    __syncthreads();
    for (int off = 1; off < 1024; off <<= 1) {
        int x = (t >= off) ? tmp[t - off] : 0;
        __syncthreads();
        tmp[t] += x;
        __syncthreads();
    }
    if (t < nslab) { int ex = tmp[t] - v; starts[t] = ex; cursors[t] = ex; }
    if (t == nslab - 1) starts[nslab] = tmp[t];
}

// Tile-local grouping: per 16384-edge tile, count per slab in LDS, reserve a
// contiguous global range per (tile, slab) with ONE atomic, then scatter
// packed words.  Writes land in ~21-entry (84 B) runs -> little amplification.
__global__ void partition_kernel(const int* __restrict__ src,
                                 const int* __restrict__ dst,
                                 int* __restrict__ cursors,
                                 unsigned int* __restrict__ packed,
                                 int n_edges, int nslab) {
    __shared__ int cnt[MAX_SLABS];
    __shared__ int base[MAX_SLABS];
    __shared__ int pos[MAX_SLABS];
    int ntiles = (n_edges + PART_T - 1) / PART_T;
    for (int tile = blockIdx.x; tile < ntiles; tile += gridDim.x) {
        int t0 = tile * PART_T;
        int t1 = min(t0 + PART_T, n_edges);
        for (int i = threadIdx.x; i < nslab; i += blockDim.x) { cnt[i] = 0; pos[i] = 0; }
        __syncthreads();
        for (int i = t0 + threadIdx.x; i < t1; i += blockDim.x)
            atomicAdd(&cnt[dst[i] >> SLAB_SHIFT], 1);
        __syncthreads();
        for (int i = threadIdx.x; i < nslab; i += blockDim.x) {
            int c = cnt[i];
            base[i] = c ? atomicAdd(&cursors[i], c) : 0;
        }
        __syncthreads();
        for (int i = t0 + threadIdx.x; i < t1; i += blockDim.x) {
            int d = dst[i];
            int s = d >> SLAB_SHIFT;
            int off = atomicAdd(&pos[s], 1);
            packed[base[s] + off] =
                ((unsigned)(d & (SLAB_NODES - 1)) << 25) | (unsigned)src[i];
        }
        __syncthreads();   // cnt/pos reused next tile
    }
}

// One block per slab (512 threads = 8 waves).  LDS: stage packed edges,
// counting-sort by dst-low (hist + scan + scatter, all on-chip), then each
// wave gathers+transforms 16 nodes.
__global__ void __launch_bounds__(512, 4)
slab_gather(const float* __restrict__ feat, const int* __restrict__ starts,
            const unsigned int* __restrict__ packed,
            const float* __restrict__ W, const float* __restrict__ b,
            float* __restrict__ out, int n_nodes) {
    __shared__ float Wt[DIM * WT_LD];       // Wt[d][o] = W[o][d]
    __shared__ unsigned int raw[SLAB_CAP];
    __shared__ int srt[SLAB_CAP];
    __shared__ int cnt[SLAB_NODES];         // counts, then cursors
    __shared__ int stmp[SLAB_NODES];        // scan temp
    __shared__ int lstarts[SLAB_NODES + 1];
    __shared__ float arow[8][DIM];
    int tid = threadIdx.x;

    for (int i = tid; i < DIM * DIM; i += 512) {
        int o = i >> 6, d = i & 63;
        Wt[d * WT_LD + o] = W[i];           // banks (d+o)%32 within wave: 2-way
    }
    int slab = blockIdx.x;
    int e0 = starts[slab], e1 = starts[slab + 1];
    int ce = min(e1 - e0, SLAB_CAP);
    for (int k = tid; k < ce; k += 512) raw[k] = packed[e0 + k];
    if (tid < SLAB_NODES) cnt[tid] = 0;
    __syncthreads();

    for (int k = tid; k < ce; k += 512) atomicAdd(&cnt[raw[k] >> 25], 1);
    __syncthreads();

    int myv = (tid < SLAB_NODES) ? cnt[tid] : 0;
    if (tid < SLAB_NODES) stmp[tid] = myv;
    __syncthreads();
    for (int off = 1; off < SLAB_NODES; off <<= 1) {
        int x = 0;
        if (tid < SLAB_NODES && tid >= off) x = stmp[tid - off];
        __syncthreads();
        if (tid < SLAB_NODES) stmp[tid] += x;
        __syncthreads();
    }
    if (tid < SLAB_NODES) { lstarts[tid + 1] = stmp[tid]; cnt[tid] = stmp[tid] - myv; }
    if (tid == 0) lstarts[0] = 0;
    __syncthreads();

    for (int k = tid; k < ce; k += 512) {
        unsigned int v = raw[k];
        int nl = (int)(v >> 25);
        int p = atomicAdd(&cnt[nl], 1);
        srt[p] = (int)(v & 0x1FFFFFFu);
    }
    __syncthreads();

    int wave = tid >> 6, lane = tid & 63;
    int sub = lane >> 4;       // 0..3 edge group
    int part = lane & 15;      // float4 column chunk
    float bl = b[lane];
    int node0 = slab * SLAB_NODES;
    int nsn = min(SLAB_NODES, n_nodes - node0);
    const float4* f4 = (const float4*)feat;

    for (int nl = wave; nl < nsn; nl += 8) {
        int a0 = lstarts[nl], a1 = lstarts[nl + 1];
        float4 acc = make_float4(0.f, 0.f, 0.f, 0.f);
        float4 acc2 = make_float4(0.f, 0.f, 0.f, 0.f);
        int e = a0 + sub;
        for (; e + 4 < a1; e += 8) {
            int s0 = srt[e];
            int s1 = srt[e + 4];
            float4 v0 = f4[(long)s0 * 16 + part];
            float4 v1 = f4[(long)s1 * 16 + part];
            acc.x += v0.x; acc.y += v0.y; acc.z += v0.z; acc.w += v0.w;
            acc2.x += v1.x; acc2.y += v1.y; acc2.z += v1.z; acc2.w += v1.w;
        }
        if (e < a1) {
            int s0 = srt[e];
            float4 v0 = f4[(long)s0 * 16 + part];
            acc.x += v0.x; acc.y += v0.y; acc.z += v0.z; acc.w += v0.w;
        }
        acc.x += acc2.x; acc.y += acc2.y; acc.z += acc2.z; acc.w += acc2.w;

#pragma unroll
        for (int m = 16; m <= 32; m <<= 1) {
            acc.x += __shfl_xor(acc.x, m);
            acc.y += __shfl_xor(acc.y, m);
            acc.z += __shfl_xor(acc.z, m);
            acc.w += __shfl_xor(acc.w, m);
        }
        if (sub == 0) *(float4*)(&arow[wave][part * 4]) = acc;
        // same-wave LDS write->read; compiler inserts lgkmcnt wait, no barrier.

        float r = bl;
#pragma unroll
        for (int dd = 0; dd < 16; ++dd) {
            float4 a4 = *(const float4*)(&arow[wave][dd * 4]);   // broadcast
            r += a4.x * Wt[(dd * 4 + 0) * WT_LD + lane];
            r += a4.y * Wt[(dd * 4 + 1) * WT_LD + lane];
            r += a4.z * Wt[(dd * 4 + 2) * WT_LD + lane];
            r += a4.w * Wt[(dd * 4 + 3) * WT_LD + lane];
        }
        out[(long)(node0 + nl) * DIM + lane] = r;
    }
}

extern "C" void kernel_launch(void* const* d_in, const int* in_sizes, int n_in,
                              void* d_out, int out_size, void* d_ws, size_t ws_size,
                              hipStream_t stream) {
    const float* feat = (const float*)d_in[0];
    const int*   src  = (const int*)d_in[1];
    const int*   dst  = (const int*)d_in[2];
    const float* W    = (const float*)d_in[3];
    const float* b    = (const float*)d_in[4];
    float* out = (float*)d_out;

    int n_nodes = in_sizes[0] / DIM;
    int n_edges = in_sizes[1];
    int nslab = (n_nodes + SLAB_NODES - 1) / SLAB_NODES;   // 782

    // workspace layout
    char* ws = (char*)d_ws;
    size_t off = 0;
    int* counts = (int*)(ws + off);            off += (size_t)MAX_SLABS * 4;
    int* starts = (int*)(ws + off);            off += (size_t)(MAX_SLABS + 1) * 4;
    int* cursors = (int*)(ws + off);           off += (size_t)MAX_SLABS * 4;
    off = (off + 255) & ~(size_t)255;
    unsigned int* packed = (unsigned int*)(ws + off);      // n_edges u32

    zero_counts<<<1, 1024, 0, stream>>>(counts);
    slab_hist<<<128, 256, 0, stream>>>(dst, counts, n_edges, nslab);
    scan_slabs<<<1, 1024, 0, stream>>>(counts, starts, cursors, nslab);
    int ntiles = (n_edges + PART_T - 1) / PART_T;
    partition_kernel<<<ntiles, 256, 0, stream>>>(src, dst, cursors, packed,
                                                 n_edges, nslab);
    slab_gather<<<nslab, 512, 0, stream>>>(feat, starts, packed, W, b, out, n_nodes);
}

// Round 6
// 106.191 us; speedup vs baseline: 10.1184x; 1.2354x over previous
//
#include <hip/hip_runtime.h>

// GNN layer: out = segment_sum(feat[src], dst) @ W^T + b
// Slab design: edges partitioned into 128-node slabs by dst (tile-local LDS
// counting + one-atomic bulk reservation per (tile,slab)), then per-slab
// blocks counting-sort their ~1280 edges in LDS and run the fused gather +
// 64x64 linear.  Packed edge word: (dst&127)<<25 | src (src < 2^17).
// Round 6: partition tile 16384 -> 2048 (62 -> 489 blocks; round-5 counters
// showed partition at 2% occupancy / 0.6% VALUBusy = launch-shape bound).

#define DIM 64
#define WT_LD 65          // padded: 65 % 32 == 1 -> conflict-free transpose
#define SLAB_SHIFT 7
#define SLAB_NODES 128
#define MAX_SLABS 800     // >= ceil(100000/128) = 782
#define SLAB_CAP 2048     // LDS capacity of edges per slab (avg 1280, +21 sigma)
#define PART_T 2048       // edges per partition tile

__global__ void zero_counts(int* __restrict__ counts) {
    int t = threadIdx.x;
    if (t < MAX_SLABS) counts[t] = 0;
}

__global__ void slab_hist(const int* __restrict__ dst, int* __restrict__ counts,
                          int n_edges, int nslab) {
    __shared__ int c[MAX_SLABS];
    for (int i = threadIdx.x; i < nslab; i += blockDim.x) c[i] = 0;
    __syncthreads();
    int n4 = n_edges >> 2;
    const int4* d4 = (const int4*)dst;
    for (int i = blockIdx.x * blockDim.x + threadIdx.x; i < n4;
         i += gridDim.x * blockDim.x) {
        int4 d = d4[i];
        atomicAdd(&c[d.x >> SLAB_SHIFT], 1);
        atomicAdd(&c[d.y >> SLAB_SHIFT], 1);
        atomicAdd(&c[d.z >> SLAB_SHIFT], 1);
        atomicAdd(&c[d.w >> SLAB_SHIFT], 1);
    }
    int base = n4 << 2;
    int r = base + blockIdx.x * blockDim.x + threadIdx.x;
    if (r < n_edges) atomicAdd(&c[dst[r] >> SLAB_SHIFT], 1);
    __syncthreads();
    for (int i = threadIdx.x; i < nslab; i += blockDim.x)
        if (c[i]) atomicAdd(&counts[i], c[i]);
}

// Single-block exclusive scan of nslab (<=1024) counts -> starts & cursors.
__global__ void scan_slabs(const int* __restrict__ counts, int* __restrict__ starts,
                           int* __restrict__ cursors, int nslab) {
    __shared__ int tmp[1024];
    int t = threadIdx.x;
    int v = (t < nslab) ? counts[t] : 0;
    tmp[t] = v;
    __syncthreads();
    for (int off = 1; off < 1024; off <<= 1) {
        int x = (t >= off) ? tmp[t - off] : 0;
        __syncthreads();
        tmp[t] += x;
        __syncthreads();
    }
    if (t < nslab) { int ex = tmp[t] - v; starts[t] = ex; cursors[t] = ex; }
    if (t == nslab - 1) starts[nslab] = tmp[t];
}

// Tile-local grouping: per 2048-edge tile, count per slab in LDS, reserve a
// contiguous global range per (tile, slab) with ONE atomic, then scatter
// packed words.
__global__ void partition_kernel(const int* __restrict__ src,
                                 const int* __restrict__ dst,
                                 int* __restrict__ cursors,
                                 unsigned int* __restrict__ packed,
                                 int n_edges, int nslab) {
    __shared__ int cnt[MAX_SLABS];
    __shared__ int base[MAX_SLABS];
    __shared__ int pos[MAX_SLABS];
    int ntiles = (n_edges + PART_T - 1) / PART_T;
    for (int tile = blockIdx.x; tile < ntiles; tile += gridDim.x) {
        int t0 = tile * PART_T;
        int t1 = min(t0 + PART_T, n_edges);
        for (int i = threadIdx.x; i < nslab; i += blockDim.x) { cnt[i] = 0; pos[i] = 0; }
        __syncthreads();
        for (int i = t0 + threadIdx.x; i < t1; i += blockDim.x)
            atomicAdd(&cnt[dst[i] >> SLAB_SHIFT], 1);
        __syncthreads();
        for (int i = threadIdx.x; i < nslab; i += blockDim.x) {
            int c = cnt[i];
            base[i] = c ? atomicAdd(&cursors[i], c) : 0;
        }
        __syncthreads();
        for (int i = t0 + threadIdx.x; i < t1; i += blockDim.x) {
            int d = dst[i];
            int s = d >> SLAB_SHIFT;
            int off = atomicAdd(&pos[s], 1);
            packed[base[s] + off] =
                ((unsigned)(d & (SLAB_NODES - 1)) << 25) | (unsigned)src[i];
        }
        __syncthreads();   // cnt/pos reused next tile
    }
}

// One block per slab (512 threads = 8 waves).  LDS: stage packed edges,
// counting-sort by dst-low (hist + scan + scatter, all on-chip), then each
// wave gathers+transforms 16 nodes.
__global__ void __launch_bounds__(512, 4)
slab_gather(const float* __restrict__ feat, const int* __restrict__ starts,
            const unsigned int* __restrict__ packed,
            const float* __restrict__ W, const float* __restrict__ b,
            float* __restrict__ out, int n_nodes) {
    __shared__ float Wt[DIM * WT_LD];       // Wt[d][o] = W[o][d]
    __shared__ unsigned int raw[SLAB_CAP];
    __shared__ int srt[SLAB_CAP];
    __shared__ int cnt[SLAB_NODES];         // counts, then cursors
    __shared__ int stmp[SLAB_NODES];        // scan temp
    __shared__ int lstarts[SLAB_NODES + 1];
    __shared__ float arow[8][DIM];
    int tid = threadIdx.x;

    for (int i = tid; i < DIM * DIM; i += 512) {
        int o = i >> 6, d = i & 63;
        Wt[d * WT_LD + o] = W[i];           // banks (d+o)%32 within wave: 2-way
    }
    int slab = blockIdx.x;
    int e0 = starts[slab], e1 = starts[slab + 1];
    int ce = min(e1 - e0, SLAB_CAP);
    for (int k = tid; k < ce; k += 512) raw[k] = packed[e0 + k];
    if (tid < SLAB_NODES) cnt[tid] = 0;
    __syncthreads();

    for (int k = tid; k < ce; k += 512) atomicAdd(&cnt[raw[k] >> 25], 1);
    __syncthreads();

    int myv = (tid < SLAB_NODES) ? cnt[tid] : 0;
    if (tid < SLAB_NODES) stmp[tid] = myv;
    __syncthreads();
    for (int off = 1; off < SLAB_NODES; off <<= 1) {
        int x = 0;
        if (tid < SLAB_NODES && tid >= off) x = stmp[tid - off];
        __syncthreads();
        if (tid < SLAB_NODES) stmp[tid] += x;
        __syncthreads();
    }
    if (tid < SLAB_NODES) { lstarts[tid + 1] = stmp[tid]; cnt[tid] = stmp[tid] - myv; }
    if (tid == 0) lstarts[0] = 0;
    __syncthreads();

    for (int k = tid; k < ce; k += 512) {
        unsigned int v = raw[k];
        int nl = (int)(v >> 25);
        int p = atomicAdd(&cnt[nl], 1);
        srt[p] = (int)(v & 0x1FFFFFFu);
    }
    __syncthreads();

    int wave = tid >> 6, lane = tid & 63;
    int sub = lane >> 4;       // 0..3 edge group
    int part = lane & 15;      // float4 column chunk
    float bl = b[lane];
    int node0 = slab * SLAB_NODES;
    int nsn = min(SLAB_NODES, n_nodes - node0);
    const float4* f4 = (const float4*)feat;

    for (int nl = wave; nl < nsn; nl += 8) {
        int a0 = lstarts[nl], a1 = lstarts[nl + 1];
        float4 acc = make_float4(0.f, 0.f, 0.f, 0.f);
        float4 acc2 = make_float4(0.f, 0.f, 0.f, 0.f);
        int e = a0 + sub;
        for (; e + 4 < a1; e += 8) {
            int s0 = srt[e];
            int s1 = srt[e + 4];
            float4 v0 = f4[(long)s0 * 16 + part];
            float4 v1 = f4[(long)s1 * 16 + part];
            acc.x += v0.x; acc.y += v0.y; acc.z += v0.z; acc.w += v0.w;
            acc2.x += v1.x; acc2.y += v1.y; acc2.z += v1.z; acc2.w += v1.w;
        }
        if (e < a1) {
            int s0 = srt[e];
            float4 v0 = f4[(long)s0 * 16 + part];
            acc.x += v0.x; acc.y += v0.y; acc.z += v0.z; acc.w += v0.w;
        }
        acc.x += acc2.x; acc.y += acc2.y; acc.z += acc2.z; acc.w += acc2.w;

#pragma unroll
        for (int m = 16; m <= 32; m <<= 1) {
            acc.x += __shfl_xor(acc.x, m);
            acc.y += __shfl_xor(acc.y, m);
            acc.z += __shfl_xor(acc.z, m);
            acc.w += __shfl_xor(acc.w, m);
        }
        if (sub == 0) *(float4*)(&arow[wave][part * 4]) = acc;
        // same-wave LDS write->read; compiler inserts lgkmcnt wait, no barrier.

        float r = bl;
#pragma unroll
        for (int dd = 0; dd < 16; ++dd) {
            float4 a4 = *(const float4*)(&arow[wave][dd * 4]);   // broadcast
            r += a4.x * Wt[(dd * 4 + 0) * WT_LD + lane];
            r += a4.y * Wt[(dd * 4 + 1) * WT_LD + lane];
            r += a4.z * Wt[(dd * 4 + 2) * WT_LD + lane];
            r += a4.w * Wt[(dd * 4 + 3) * WT_LD + lane];
        }
        out[(long)(node0 + nl) * DIM + lane] = r;
    }
}

extern "C" void kernel_launch(void* const* d_in, const int* in_sizes, int n_in,
                              void* d_out, int out_size, void* d_ws, size_t ws_size,
                              hipStream_t stream) {
    const float* feat = (const float*)d_in[0];
    const int*   src  = (const int*)d_in[1];
    const int*   dst  = (const int*)d_in[2];
    const float* W    = (const float*)d_in[3];
    const float* b    = (const float*)d_in[4];
    float* out = (float*)d_out;

    int n_nodes = in_sizes[0] / DIM;
    int n_edges = in_sizes[1];
    int nslab = (n_nodes + SLAB_NODES - 1) / SLAB_NODES;   // 782

    // workspace layout
    char* ws = (char*)d_ws;
    size_t off = 0;
    int* counts = (int*)(ws + off);            off += (size_t)MAX_SLABS * 4;
    int* starts = (int*)(ws + off);            off += (size_t)(MAX_SLABS + 1) * 4;
    int* cursors = (int*)(ws + off);           off += (size_t)MAX_SLABS * 4;
    off = (off + 255) & ~(size_t)255;
    unsigned int* packed = (unsigned int*)(ws + off);      // n_edges u32

    zero_counts<<<1, 1024, 0, stream>>>(counts);
    slab_hist<<<256, 256, 0, stream>>>(dst, counts, n_edges, nslab);
    scan_slabs<<<1, 1024, 0, stream>>>(counts, starts, cursors, nslab);
    int ntiles = (n_edges + PART_T - 1) / PART_T;
    partition_kernel<<<ntiles, 256, 0, stream>>>(src, dst, cursors, packed,
                                                 n_edges, nslab);
    slab_gather<<<nslab, 512, 0, stream>>>(feat, starts, packed, W, b, out, n_nodes);
}